// Round 5
// baseline (250.705 us; speedup 1.0000x reference)
//
#include <hip/hip_runtime.h>

#define DD 128

typedef _Float16 f16;
typedef __attribute__((ext_vector_type(8))) _Float16 v8h;
typedef __attribute__((ext_vector_type(4))) _Float16 v4h;
typedef __attribute__((ext_vector_type(4))) float f32x4;

static inline int cdiv(int a, int b) { return (a + b - 1) / b; }

// ---------------- small utility ----------------

__global__ __launch_bounds__(256) void zero_kernel(int* __restrict__ p, int n) {
    int i = blockIdx.x * 256 + threadIdx.x;
    if (i < n) p[i] = 0;
}

// ---------------- CSR build ----------------

__global__ __launch_bounds__(256) void count_kernel(const int* __restrict__ dst, int E,
                                                    int* __restrict__ cnt) {
    int e = blockIdx.x * 256 + threadIdx.x;
    if (e < E) atomicAdd(&cnt[dst[e]], 1);
}

__global__ __launch_bounds__(256) void scan1(const int* __restrict__ cnt, int N,
                                             int* __restrict__ bsum) {
    __shared__ int s[256];
    int i = blockIdx.x * 256 + threadIdx.x;
    s[threadIdx.x] = (i < N) ? cnt[i] : 0;
    __syncthreads();
    for (int off = 128; off > 0; off >>= 1) {
        if (threadIdx.x < off) s[threadIdx.x] += s[threadIdx.x + off];
        __syncthreads();
    }
    if (threadIdx.x == 0) bsum[blockIdx.x] = s[0];
}

__global__ __launch_bounds__(512) void scan2(const int* __restrict__ bsum, int NB,
                                             int* __restrict__ boff) {
    __shared__ int s[512];
    int t = threadIdx.x;
    int v = (t < NB) ? bsum[t] : 0;
    s[t] = v;
    __syncthreads();
    for (int off = 1; off < 512; off <<= 1) {
        int x = (t >= off) ? s[t - off] : 0;
        __syncthreads();
        s[t] += x;
        __syncthreads();
    }
    if (t < NB) boff[t] = s[t] - v;  // exclusive
}

__global__ __launch_bounds__(256) void scan3(const int* __restrict__ cnt,
                                             const int* __restrict__ boff, int N,
                                             int* __restrict__ off) {
    __shared__ int s[256];
    int t = threadIdx.x;
    int i = blockIdx.x * 256 + t;
    int v = (i < N) ? cnt[i] : 0;
    s[t] = v;
    __syncthreads();
    for (int o = 1; o < 256; o <<= 1) {
        int x = (t >= o) ? s[t - o] : 0;
        __syncthreads();
        s[t] += x;
        __syncthreads();
    }
    int excl = s[t] - v + boff[blockIdx.x];
    if (i < N) off[i] = excl;
    if (i == N - 1) off[N] = excl + v;
}

__global__ __launch_bounds__(256) void fill_kernel(const int* __restrict__ src,
                                                   const int* __restrict__ dst, int E,
                                                   const int* __restrict__ off,
                                                   int* __restrict__ cnt,
                                                   int* __restrict__ csr) {
    int e = blockIdx.x * 256 + threadIdx.x;
    if (e < E) {
        int d = dst[e];
        int p = atomicSub(&cnt[d], 1) - 1;  // unique slot within [0, deg)
        csr[off[d] + p] = src[e];
    }
}

// ---------------- weight fp32 -> f16 conversion (6 matrices of 128x128) ----------------

__global__ __launch_bounds__(256) void cvt_w_kernel(const float* __restrict__ W0,
                                                    const float* __restrict__ W1,
                                                    const float* __restrict__ W2,
                                                    const float* __restrict__ W3,
                                                    const float* __restrict__ W4,
                                                    const float* __restrict__ W5,
                                                    f16* __restrict__ out) {
    int mat = blockIdx.x >> 4;  // 16 blocks per matrix (16384 elems / (256*4))
    const float* W = mat == 0 ? W0 : mat == 1 ? W1 : mat == 2 ? W2
                   : mat == 3 ? W3 : mat == 4 ? W4 : W5;
    int base = (blockIdx.x & 15) * 1024 + threadIdx.x * 4;
    float4 v = *(const float4*)(W + base);
    v4h o;
    o[0] = (f16)v.x; o[1] = (f16)v.y; o[2] = (f16)v.z; o[3] = (f16)v.w;
    *(v4h*)(out + mat * 16384 + base) = o;
}

// ---------------- shared GEMM helpers ----------------
// mfma_f32_16x16x32_f16: A frag lane l -> A[row=l&15][k=(l>>4)*8+j] (8 contig f16)
//                        B frag lane l -> W[col=l&15][k=(l>>4)*8+j] (8 contig f16)
//                        D lane l reg j -> D[row=(l>>4)*4+j][col=l&15]

// Stage 128x128 f16 W into LDS, chunk-swizzled: chunk (16B) sc = c16 ^ (col&7)
__device__ inline void stage_w(const f16* __restrict__ Wg, f16* __restrict__ smem, int t) {
#pragma unroll
    for (int i = 0; i < 8; ++i) {
        int idx16 = i * 256 + t;
        int col = idx16 >> 4, c16 = idx16 & 15;
        int sc = c16 ^ (col & 7);
        uint4 v = *(const uint4*)(Wg + idx16 * 8);
        *(uint4*)(smem + col * DD + sc * 8) = v;
    }
}

__device__ inline v8h read_b(const f16* __restrict__ smem, int ct, int ki, int l) {
    int col = ct * 16 + (l & 15);
    int c16 = ki * 4 + (l >> 4);
    int sc = c16 ^ (col & 7);
    return *(const v8h*)(smem + col * DD + sc * 8);
}

__device__ inline v8h load_frag16(const f16* __restrict__ A, int row, int kb, int M) {
    if (row >= M) {
        v8h z = {};
        return z;
    }
    return *(const v8h*)(A + (size_t)row * DD + kb);
}

// ---------------- projection GEMM: OUT = relu(A @ W^T + bias) ----------------
// WX: also write the f16-converted A fragments to A16 (x -> x16 side output).

template <typename TA, bool WX>
__global__ __launch_bounds__(256) void mgemm(const TA* __restrict__ A,
                                             const f16* __restrict__ W1,
                                             const float* __restrict__ bias,
                                             f16* __restrict__ OUT,
                                             f16* __restrict__ A16, int M) {
    __shared__ f16 WS[DD * DD];
    int t = threadIdx.x, l = t & 63, w = t >> 6;
    int row0 = blockIdx.x * 128 + w * 32;
    int r = l & 15, cg = l >> 4;

    stage_w(W1, WS, t);

    v8h af[2][4];
#pragma unroll
    for (int rt = 0; rt < 2; ++rt) {
        int row = row0 + rt * 16 + r;
#pragma unroll
        for (int ki = 0; ki < 4; ++ki) {
            int kb = ki * 32 + cg * 8;
            if constexpr (sizeof(TA) == 2) {
                af[rt][ki] = load_frag16(A, row, kb, M);
            } else {
                if (row < M) {
                    float4 a = *(const float4*)(A + (size_t)row * DD + kb);
                    float4 b = *(const float4*)(A + (size_t)row * DD + kb + 4);
                    v8h rr;
                    rr[0] = (f16)a.x; rr[1] = (f16)a.y; rr[2] = (f16)a.z; rr[3] = (f16)a.w;
                    rr[4] = (f16)b.x; rr[5] = (f16)b.y; rr[6] = (f16)b.z; rr[7] = (f16)b.w;
                    af[rt][ki] = rr;
                } else {
                    v8h z = {};
                    af[rt][ki] = z;
                }
            }
            if constexpr (WX) {
                if (row < M) *(v8h*)(A16 + (size_t)row * DD + kb) = af[rt][ki];
            }
        }
    }
    __syncthreads();

    f32x4 acc[2][8];
#pragma unroll
    for (int ct = 0; ct < 8; ++ct) {
        float bv = bias[ct * 16 + r];
        f32x4 b4 = {bv, bv, bv, bv};
        acc[0][ct] = b4;
        acc[1][ct] = b4;
    }

#pragma unroll
    for (int ct = 0; ct < 8; ++ct)
#pragma unroll
        for (int ki = 0; ki < 4; ++ki) {
            v8h b = read_b(WS, ct, ki, l);
            acc[0][ct] = __builtin_amdgcn_mfma_f32_16x16x32_f16(af[0][ki], b, acc[0][ct], 0, 0, 0);
            acc[1][ct] = __builtin_amdgcn_mfma_f32_16x16x32_f16(af[1][ki], b, acc[1][ct], 0, 0, 0);
        }

#pragma unroll
    for (int rt = 0; rt < 2; ++rt)
#pragma unroll
        for (int ct = 0; ct < 8; ++ct)
#pragma unroll
            for (int j = 0; j < 4; ++j) {
                int row = row0 + rt * 16 + cg * 4 + j;
                if (row < M)
                    OUT[(size_t)row * DD + ct * 16 + r] = (f16)fmaxf(acc[rt][ct][j], 0.f);
            }
}

// ---------------- fused aggregate + dual GEMM ----------------
// OUT = act(mean(H[neighbors]) @ Wl^T + bias + Xr @ Wr^T)
// Each lane accumulates its own MFMA A-fragment slice of the mean directly:
// lane l owns row (l&15 [+16*rt]) cols {cg*8+ki*32+j}. Per gather step one
// wave instruction reads 16 random rows x 64B -> full cache lines.

template <typename TO, bool RELU>
__global__ __launch_bounds__(256) void agg_mgemm(const f16* __restrict__ H,
                                                 const int* __restrict__ off,
                                                 const int* __restrict__ csr,
                                                 const f16* __restrict__ Wl,
                                                 const float* __restrict__ bias,
                                                 const f16* __restrict__ Xr,
                                                 const f16* __restrict__ Wr,
                                                 TO* __restrict__ OUT, int M) {
    __shared__ f16 WS[2 * DD * DD];  // 64KB: Wl | Wr
    int t = threadIdx.x, l = t & 63, w = t >> 6;
    int row0 = blockIdx.x * 128 + w * 32;
    int r = l & 15, cg = l >> 4;

    stage_w(Wl, WS, t);
    stage_w(Wr, WS + DD * DD, t);

    // root fragments early (independent; overlap with gathers)
    v8h af2[2][4];
#pragma unroll
    for (int rt = 0; rt < 2; ++rt)
#pragma unroll
        for (int ki = 0; ki < 4; ++ki)
            af2[rt][ki] = load_frag16(Xr, row0 + rt * 16 + r, ki * 32 + cg * 8, M);

    // aggregate neighbors into this lane's fragment slice (f32 accum)
    float ag[2][4][8];
#pragma unroll
    for (int rt = 0; rt < 2; ++rt)
#pragma unroll
        for (int ki = 0; ki < 4; ++ki)
#pragma unroll
            for (int j = 0; j < 8; ++j) ag[rt][ki][j] = 0.f;

    float inv[2] = {0.f, 0.f};
#pragma unroll
    for (int rt = 0; rt < 2; ++rt) {
        int row = row0 + rt * 16 + r;
        if (row < M) {
            int s = off[row], e = off[row + 1];
            for (int i = s; i < e; ++i) {
                int idx = csr[i];
                const f16* hp = H + (size_t)idx * DD + cg * 8;
#pragma unroll
                for (int ki = 0; ki < 4; ++ki) {
                    v8h v = *(const v8h*)(hp + ki * 32);
#pragma unroll
                    for (int j = 0; j < 8; ++j) ag[rt][ki][j] += (float)v[j];
                }
            }
            int deg = e - s;
            inv[rt] = 1.0f / (float)(deg > 0 ? deg : 1);
        }
    }

    // normalize + pack to f16 A-fragments (same rounding as the old mean buffer)
    v8h paf[2][4];
#pragma unroll
    for (int rt = 0; rt < 2; ++rt)
#pragma unroll
        for (int ki = 0; ki < 4; ++ki) {
            v8h p;
#pragma unroll
            for (int j = 0; j < 8; ++j) p[j] = (f16)(ag[rt][ki][j] * inv[rt]);
            paf[rt][ki] = p;
        }

    __syncthreads();  // W staging visible (long since issued)

    f32x4 acc[2][8];
#pragma unroll
    for (int ct = 0; ct < 8; ++ct) {
        float bv = bias[ct * 16 + r];
        f32x4 b4 = {bv, bv, bv, bv};
        acc[0][ct] = b4;
        acc[1][ct] = b4;
    }

#pragma unroll
    for (int ct = 0; ct < 8; ++ct)
#pragma unroll
        for (int ki = 0; ki < 4; ++ki) {
            v8h b1 = read_b(WS, ct, ki, l);
            acc[0][ct] = __builtin_amdgcn_mfma_f32_16x16x32_f16(paf[0][ki], b1, acc[0][ct], 0, 0, 0);
            acc[1][ct] = __builtin_amdgcn_mfma_f32_16x16x32_f16(paf[1][ki], b1, acc[1][ct], 0, 0, 0);
            v8h b2 = read_b(WS + DD * DD, ct, ki, l);
            acc[0][ct] = __builtin_amdgcn_mfma_f32_16x16x32_f16(af2[0][ki], b2, acc[0][ct], 0, 0, 0);
            acc[1][ct] = __builtin_amdgcn_mfma_f32_16x16x32_f16(af2[1][ki], b2, acc[1][ct], 0, 0, 0);
        }

#pragma unroll
    for (int rt = 0; rt < 2; ++rt)
#pragma unroll
        for (int ct = 0; ct < 8; ++ct)
#pragma unroll
            for (int j = 0; j < 4; ++j) {
                int row = row0 + rt * 16 + cg * 4 + j;
                if (row < M) {
                    float v = acc[rt][ct][j];
                    if (RELU) v = fmaxf(v, 0.f);
                    OUT[(size_t)row * DD + ct * 16 + r] = (TO)v;
                }
            }
}

// ---------------- launch ----------------

extern "C" void kernel_launch(void* const* d_in, const int* in_sizes, int n_in,
                              void* d_out, int out_size, void* d_ws, size_t ws_size,
                              hipStream_t stream) {
    const float* x = (const float*)d_in[0];
    const int* ei = (const int*)d_in[1];
    const float* Wp0 = (const float*)d_in[2];
    const float* bp0 = (const float*)d_in[3];
    const float* Wl0 = (const float*)d_in[4];
    const float* bl0 = (const float*)d_in[5];
    const float* Wr0 = (const float*)d_in[6];
    const float* Wp1 = (const float*)d_in[7];
    const float* bp1 = (const float*)d_in[8];
    const float* Wl1 = (const float*)d_in[9];
    const float* bl1 = (const float*)d_in[10];
    const float* Wr1 = (const float*)d_in[11];

    int N = in_sizes[0] / DD;
    int E = in_sizes[1] / 2;
    const int* src = ei;
    const int* dst = ei + E;

    // ---- workspace (~54.5MB, matches round-3's proven-safe footprint) ----
    // d_out timeline: [h: lower 25.6MB][x16: upper 25.6MB] — both READ-only
    // for fused gemm2, then fully rewritten by fused gemm4 (which gathers
    // from h2 in ws, NOT d_out -> no read/write race).
    char* ws = (char*)d_ws;
    size_t o = 0;
    auto alloc = [&](size_t bytes) {
        size_t r = o;
        o = (o + bytes + 255) & ~(size_t)255;
        return r;
    };
    f16* w16 = (f16*)(ws + alloc((size_t)6 * DD * DD * 2));
    int* cnt = (int*)(ws + alloc((size_t)N * 4));
    int* off = (int*)(ws + alloc((size_t)(N + 1) * 4));
    int NB = cdiv(N, 256);
    int* bsum = (int*)(ws + alloc((size_t)NB * 4));
    int* boff = (int*)(ws + alloc((size_t)NB * 4));
    int* csr = (int*)(ws + alloc((size_t)E * 4));
    f16* y1 = (f16*)(ws + alloc((size_t)N * DD * 2));
    f16* h2 = (f16*)(ws + alloc((size_t)N * DD * 2));
    f16* h = (f16*)d_out;                                  // lower half of d_out
    f16* x16 = (f16*)((char*)d_out + (size_t)N * DD * 2);  // upper half of d_out
    (void)ws_size;

    // CSR build (shared by both layers)
    zero_kernel<<<NB, 256, 0, stream>>>(cnt, N);
    count_kernel<<<cdiv(E, 256), 256, 0, stream>>>(dst, E, cnt);
    scan1<<<NB, 256, 0, stream>>>(cnt, N, bsum);
    scan2<<<1, 512, 0, stream>>>(bsum, NB, boff);
    scan3<<<NB, 256, 0, stream>>>(cnt, boff, N, off);
    fill_kernel<<<cdiv(E, 256), 256, 0, stream>>>(src, dst, E, off, cnt, csr);

    // weights -> f16 once: order [Wp0, Wl0, Wr0, Wp1, Wl1, Wr1]
    cvt_w_kernel<<<96, 256, 0, stream>>>(Wp0, Wl0, Wr0, Wp1, Wl1, Wr1, w16);
    const f16* wp0 = w16 + 0 * 16384;
    const f16* wl0 = w16 + 1 * 16384;
    const f16* wr0 = w16 + 2 * 16384;
    const f16* wp1 = w16 + 3 * 16384;
    const f16* wl1 = w16 + 4 * 16384;
    const f16* wr1 = w16 + 5 * 16384;

    int GB = cdiv(N, 128);
    // layer 1: proj (+x16 side output), then fused agg+lin_l+lin_r
    mgemm<float, true><<<GB, 256, 0, stream>>>(x, wp0, bp0, h, x16, N);
    agg_mgemm<f16, true>
        <<<GB, 256, 0, stream>>>(h, off, csr, wl0, bl0, x16, wr0, y1, N);
    // layer 2
    mgemm<f16, false><<<GB, 256, 0, stream>>>(y1, wp1, bp1, h2, nullptr, N);
    agg_mgemm<float, false>
        <<<GB, 256, 0, stream>>>(h2, off, csr, wl1, bl1, y1, wr1, (float*)d_out, N);
}

// Round 6
// 242.604 us; speedup vs baseline: 1.0334x; 1.0334x over previous
//
#include <hip/hip_runtime.h>

#define DD 128

typedef _Float16 f16;
typedef __attribute__((ext_vector_type(8))) _Float16 v8h;
typedef __attribute__((ext_vector_type(4))) _Float16 v4h;
typedef __attribute__((ext_vector_type(4))) float f32x4;

static inline int cdiv(int a, int b) { return (a + b - 1) / b; }

// ---------------- small utility ----------------

__global__ __launch_bounds__(256) void zero_kernel(int* __restrict__ p, int n) {
    int i = blockIdx.x * 256 + threadIdx.x;
    if (i < n) p[i] = 0;
}

// ---------------- CSR build ----------------

__global__ __launch_bounds__(256) void count_kernel(const int* __restrict__ dst, int E,
                                                    int* __restrict__ cnt) {
    int e = blockIdx.x * 256 + threadIdx.x;
    if (e < E) atomicAdd(&cnt[dst[e]], 1);
}

__global__ __launch_bounds__(256) void scan1(const int* __restrict__ cnt, int N,
                                             int* __restrict__ bsum) {
    __shared__ int s[256];
    int i = blockIdx.x * 256 + threadIdx.x;
    s[threadIdx.x] = (i < N) ? cnt[i] : 0;
    __syncthreads();
    for (int off = 128; off > 0; off >>= 1) {
        if (threadIdx.x < off) s[threadIdx.x] += s[threadIdx.x + off];
        __syncthreads();
    }
    if (threadIdx.x == 0) bsum[blockIdx.x] = s[0];
}

__global__ __launch_bounds__(512) void scan2(const int* __restrict__ bsum, int NB,
                                             int* __restrict__ boff) {
    __shared__ int s[512];
    int t = threadIdx.x;
    int v = (t < NB) ? bsum[t] : 0;
    s[t] = v;
    __syncthreads();
    for (int off = 1; off < 512; off <<= 1) {
        int x = (t >= off) ? s[t - off] : 0;
        __syncthreads();
        s[t] += x;
        __syncthreads();
    }
    if (t < NB) boff[t] = s[t] - v;  // exclusive
}

__global__ __launch_bounds__(256) void scan3(const int* __restrict__ cnt,
                                             const int* __restrict__ boff, int N,
                                             int* __restrict__ off) {
    __shared__ int s[256];
    int t = threadIdx.x;
    int i = blockIdx.x * 256 + t;
    int v = (i < N) ? cnt[i] : 0;
    s[t] = v;
    __syncthreads();
    for (int o = 1; o < 256; o <<= 1) {
        int x = (t >= o) ? s[t - o] : 0;
        __syncthreads();
        s[t] += x;
        __syncthreads();
    }
    int excl = s[t] - v + boff[blockIdx.x];
    if (i < N) off[i] = excl;
    if (i == N - 1) off[N] = excl + v;
}

__global__ __launch_bounds__(256) void fill_kernel(const int* __restrict__ src,
                                                   const int* __restrict__ dst, int E,
                                                   const int* __restrict__ off,
                                                   int* __restrict__ cnt,
                                                   int* __restrict__ csr) {
    int e = blockIdx.x * 256 + threadIdx.x;
    if (e < E) {
        int d = dst[e];
        int p = atomicSub(&cnt[d], 1) - 1;  // unique slot within [0, deg)
        csr[off[d] + p] = src[e];
    }
}

// ---------------- weight fp32 -> f16 conversion (6 matrices of 128x128) ----------------

__global__ __launch_bounds__(256) void cvt_w_kernel(const float* __restrict__ W0,
                                                    const float* __restrict__ W1,
                                                    const float* __restrict__ W2,
                                                    const float* __restrict__ W3,
                                                    const float* __restrict__ W4,
                                                    const float* __restrict__ W5,
                                                    f16* __restrict__ out) {
    int mat = blockIdx.x >> 4;  // 16 blocks per matrix (16384 elems / (256*4))
    const float* W = mat == 0 ? W0 : mat == 1 ? W1 : mat == 2 ? W2
                   : mat == 3 ? W3 : mat == 4 ? W4 : W5;
    int base = (blockIdx.x & 15) * 1024 + threadIdx.x * 4;
    float4 v = *(const float4*)(W + base);
    v4h o;
    o[0] = (f16)v.x; o[1] = (f16)v.y; o[2] = (f16)v.z; o[3] = (f16)v.w;
    *(v4h*)(out + mat * 16384 + base) = o;
}

// ---------------- aggregation: mean of gathered h rows ----------------
// Wave per node; 4 groups x 16 lanes; each group gathers a full 256B row
// (16 lanes x 16B). 2-deep software pipeline -> 8 independent gather chains
// per wave (round-4 had 4; the dependent waitcnt serialized each group).

__global__ __launch_bounds__(256) void aggregate_kernel(const f16* __restrict__ h,
                                                        const int* __restrict__ off,
                                                        const int* __restrict__ csr,
                                                        f16* __restrict__ mean, int N) {
    int n = blockIdx.x * 4 + (threadIdx.x >> 6);
    int l = threadIdx.x & 63;
    int g = l >> 4, c = l & 15;
    if (n >= N) return;
    int s = off[n], e = off[n + 1];
    float acc[8] = {0.f, 0.f, 0.f, 0.f, 0.f, 0.f, 0.f, 0.f};
    int i0 = s + g;
    int i1 = i0 + 4;
    v8h v0 = {}, v1 = {};
    if (i0 < e) v0 = *(const v8h*)(h + (size_t)csr[i0] * DD + c * 8);
    if (i1 < e) v1 = *(const v8h*)(h + (size_t)csr[i1] * DD + c * 8);
    while (i0 < e) {
        int i2 = i1 + 4;
        v8h v2 = {};
        if (i2 < e) v2 = *(const v8h*)(h + (size_t)csr[i2] * DD + c * 8);
#pragma unroll
        for (int j = 0; j < 8; ++j) acc[j] += (float)v0[j];
        v0 = v1;
        v1 = v2;
        i0 = i1;
        i1 = i2;
    }
    // reduce across the 4 groups (lanes l, l^16, l^32, l^48)
#pragma unroll
    for (int j = 0; j < 8; ++j) {
        acc[j] += __shfl_xor(acc[j], 16);
        acc[j] += __shfl_xor(acc[j], 32);
    }
    int deg = e - s;
    float inv = 1.0f / (float)(deg > 0 ? deg : 1);
    if (g == 0) {
        v8h o;
#pragma unroll
        for (int j = 0; j < 8; ++j) o[j] = (f16)(acc[j] * inv);
        *(v8h*)(mean + (size_t)n * DD + c * 8) = o;
    }
}

// ---------------- shared GEMM helpers ----------------
// mfma_f32_16x16x32_f16: A frag lane l -> A[row=l&15][k=(l>>4)*8+j] (8 contig f16)
//                        B frag lane l -> W[col=l&15][k=(l>>4)*8+j] (8 contig f16)
//                        D lane l reg j -> D[row=(l>>4)*4+j][col=l&15]

// Stage 128x128 f16 W into LDS, chunk-swizzled: chunk (16B) sc = c16 ^ (col&7)
__device__ inline void stage_w(const f16* __restrict__ Wg, f16* __restrict__ smem, int t) {
#pragma unroll
    for (int i = 0; i < 8; ++i) {
        int idx16 = i * 256 + t;
        int col = idx16 >> 4, c16 = idx16 & 15;
        int sc = c16 ^ (col & 7);
        uint4 v = *(const uint4*)(Wg + idx16 * 8);
        *(uint4*)(smem + col * DD + sc * 8) = v;
    }
}

__device__ inline v8h read_b(const f16* __restrict__ smem, int ct, int ki, int l) {
    int col = ct * 16 + (l & 15);
    int c16 = ki * 4 + (l >> 4);
    int sc = c16 ^ (col & 7);
    return *(const v8h*)(smem + col * DD + sc * 8);
}

__device__ inline v8h load_frag16(const f16* __restrict__ A, int row, int kb, int M) {
    if (row >= M) {
        v8h z = {};
        return z;
    }
    return *(const v8h*)(A + (size_t)row * DD + kb);
}

// ---------------- projection GEMM: OUT = relu(A @ W^T + bias) ----------------
// WX: also write the f16-converted A fragments to A16 (x -> x16 side output).

template <typename TA, bool WX>
__global__ __launch_bounds__(256) void proj_gemm(const TA* __restrict__ A,
                                                 const f16* __restrict__ W1,
                                                 const float* __restrict__ bias,
                                                 f16* __restrict__ OUT,
                                                 f16* __restrict__ A16, int M) {
    __shared__ f16 WS[DD * DD];
    int t = threadIdx.x, l = t & 63, w = t >> 6;
    int row0 = blockIdx.x * 128 + w * 32;
    int r = l & 15, cg = l >> 4;

    stage_w(W1, WS, t);

    v8h af[2][4];
#pragma unroll
    for (int rt = 0; rt < 2; ++rt) {
        int row = row0 + rt * 16 + r;
#pragma unroll
        for (int ki = 0; ki < 4; ++ki) {
            int kb = ki * 32 + cg * 8;
            if constexpr (sizeof(TA) == 2) {
                af[rt][ki] = load_frag16(A, row, kb, M);
            } else {
                if (row < M) {
                    float4 a = *(const float4*)(A + (size_t)row * DD + kb);
                    float4 b = *(const float4*)(A + (size_t)row * DD + kb + 4);
                    v8h rr;
                    rr[0] = (f16)a.x; rr[1] = (f16)a.y; rr[2] = (f16)a.z; rr[3] = (f16)a.w;
                    rr[4] = (f16)b.x; rr[5] = (f16)b.y; rr[6] = (f16)b.z; rr[7] = (f16)b.w;
                    af[rt][ki] = rr;
                } else {
                    v8h z = {};
                    af[rt][ki] = z;
                }
            }
            if constexpr (WX) {
                if (row < M) *(v8h*)(A16 + (size_t)row * DD + kb) = af[rt][ki];
            }
        }
    }
    __syncthreads();

    f32x4 acc[2][8];
#pragma unroll
    for (int ct = 0; ct < 8; ++ct) {
        float bv = bias[ct * 16 + r];
        f32x4 b4 = {bv, bv, bv, bv};
        acc[0][ct] = b4;
        acc[1][ct] = b4;
    }

#pragma unroll
    for (int ct = 0; ct < 8; ++ct)
#pragma unroll
        for (int ki = 0; ki < 4; ++ki) {
            v8h b = read_b(WS, ct, ki, l);
            acc[0][ct] = __builtin_amdgcn_mfma_f32_16x16x32_f16(af[0][ki], b, acc[0][ct], 0, 0, 0);
            acc[1][ct] = __builtin_amdgcn_mfma_f32_16x16x32_f16(af[1][ki], b, acc[1][ct], 0, 0, 0);
        }

#pragma unroll
    for (int rt = 0; rt < 2; ++rt)
#pragma unroll
        for (int ct = 0; ct < 8; ++ct)
#pragma unroll
            for (int j = 0; j < 4; ++j) {
                int row = row0 + rt * 16 + cg * 4 + j;
                if (row < M)
                    OUT[(size_t)row * DD + ct * 16 + r] = (f16)fmaxf(acc[rt][ct][j], 0.f);
            }
}

// ---------------- dual GEMM: OUT = act(A @ Wl^T + bias + B @ Wr^T) ----------------
// Both weight tiles staged up-front (64KB LDS), single barrier, 64 MFMAs.

template <typename TO, bool RELU>
__global__ __launch_bounds__(256) void dual_gemm(const f16* __restrict__ A,
                                                 const f16* __restrict__ Wl,
                                                 const float* __restrict__ bias,
                                                 const f16* __restrict__ B,
                                                 const f16* __restrict__ Wr,
                                                 TO* __restrict__ OUT, int M) {
    __shared__ f16 WS[2 * DD * DD];  // 64KB: Wl | Wr
    int t = threadIdx.x, l = t & 63, w = t >> 6;
    int row0 = blockIdx.x * 128 + w * 32;
    int r = l & 15, cg = l >> 4;

    stage_w(Wl, WS, t);
    stage_w(Wr, WS + DD * DD, t);

    v8h afA[2][4], afB[2][4];
#pragma unroll
    for (int rt = 0; rt < 2; ++rt)
#pragma unroll
        for (int ki = 0; ki < 4; ++ki) {
            int row = row0 + rt * 16 + r, kb = ki * 32 + cg * 8;
            afA[rt][ki] = load_frag16(A, row, kb, M);
            afB[rt][ki] = load_frag16(B, row, kb, M);
        }
    __syncthreads();

    f32x4 acc[2][8];
#pragma unroll
    for (int ct = 0; ct < 8; ++ct) {
        float bv = bias[ct * 16 + r];
        f32x4 b4 = {bv, bv, bv, bv};
        acc[0][ct] = b4;
        acc[1][ct] = b4;
    }

#pragma unroll
    for (int ct = 0; ct < 8; ++ct)
#pragma unroll
        for (int ki = 0; ki < 4; ++ki) {
            v8h b1 = read_b(WS, ct, ki, l);
            acc[0][ct] = __builtin_amdgcn_mfma_f32_16x16x32_f16(afA[0][ki], b1, acc[0][ct], 0, 0, 0);
            acc[1][ct] = __builtin_amdgcn_mfma_f32_16x16x32_f16(afA[1][ki], b1, acc[1][ct], 0, 0, 0);
            v8h b2 = read_b(WS + DD * DD, ct, ki, l);
            acc[0][ct] = __builtin_amdgcn_mfma_f32_16x16x32_f16(afB[0][ki], b2, acc[0][ct], 0, 0, 0);
            acc[1][ct] = __builtin_amdgcn_mfma_f32_16x16x32_f16(afB[1][ki], b2, acc[1][ct], 0, 0, 0);
        }

#pragma unroll
    for (int rt = 0; rt < 2; ++rt)
#pragma unroll
        for (int ct = 0; ct < 8; ++ct)
#pragma unroll
            for (int j = 0; j < 4; ++j) {
                int row = row0 + rt * 16 + cg * 4 + j;
                if (row < M) {
                    float v = acc[rt][ct][j];
                    if (RELU) v = fmaxf(v, 0.f);
                    OUT[(size_t)row * DD + ct * 16 + r] = (TO)v;
                }
            }
}

// ---------------- launch ----------------

extern "C" void kernel_launch(void* const* d_in, const int* in_sizes, int n_in,
                              void* d_out, int out_size, void* d_ws, size_t ws_size,
                              hipStream_t stream) {
    const float* x = (const float*)d_in[0];
    const int* ei = (const int*)d_in[1];
    const float* Wp0 = (const float*)d_in[2];
    const float* bp0 = (const float*)d_in[3];
    const float* Wl0 = (const float*)d_in[4];
    const float* bl0 = (const float*)d_in[5];
    const float* Wr0 = (const float*)d_in[6];
    const float* Wp1 = (const float*)d_in[7];
    const float* bp1 = (const float*)d_in[8];
    const float* Wl1 = (const float*)d_in[9];
    const float* bl1 = (const float*)d_in[10];
    const float* Wr1 = (const float*)d_in[11];

    int N = in_sizes[0] / DD;
    int E = in_sizes[1] / 2;
    const int* src = ei;
    const int* dst = ei + E;

    // ---- workspace (~54.8MB, round-3/4 proven-safe footprint) ----
    // d_out timeline: [h: lower 25.6MB][x16: upper 25.6MB]; split kernels mean
    // no kernel both gathers from d_out and writes it; final dual_gemm reads
    // only mean/y1 (ws) and rewrites all of d_out.
    char* ws = (char*)d_ws;
    size_t o = 0;
    auto alloc = [&](size_t bytes) {
        size_t r = o;
        o = (o + bytes + 255) & ~(size_t)255;
        return r;
    };
    f16* w16 = (f16*)(ws + alloc((size_t)6 * DD * DD * 2));
    int* cnt = (int*)(ws + alloc((size_t)N * 4));
    int* off = (int*)(ws + alloc((size_t)(N + 1) * 4));
    int NB = cdiv(N, 256);
    int* bsum = (int*)(ws + alloc((size_t)NB * 4));
    int* boff = (int*)(ws + alloc((size_t)NB * 4));
    int* csr = (int*)(ws + alloc((size_t)E * 4));
    f16* mean = (f16*)(ws + alloc((size_t)N * DD * 2));
    f16* y1 = (f16*)(ws + alloc((size_t)N * DD * 2));
    f16* h = (f16*)d_out;                                  // lower half of d_out
    f16* x16 = (f16*)((char*)d_out + (size_t)N * DD * 2);  // upper half of d_out
    (void)ws_size;

    // CSR build (shared by both layers)
    zero_kernel<<<NB, 256, 0, stream>>>(cnt, N);
    count_kernel<<<cdiv(E, 256), 256, 0, stream>>>(dst, E, cnt);
    scan1<<<NB, 256, 0, stream>>>(cnt, N, bsum);
    scan2<<<1, 512, 0, stream>>>(bsum, NB, boff);
    scan3<<<NB, 256, 0, stream>>>(cnt, boff, N, off);
    fill_kernel<<<cdiv(E, 256), 256, 0, stream>>>(src, dst, E, off, cnt, csr);

    // weights -> f16 once: order [Wp0, Wl0, Wr0, Wp1, Wl1, Wr1]
    cvt_w_kernel<<<96, 256, 0, stream>>>(Wp0, Wl0, Wr0, Wp1, Wl1, Wr1, w16);
    const f16* wp0 = w16 + 0 * 16384;
    const f16* wl0 = w16 + 1 * 16384;
    const f16* wr0 = w16 + 2 * 16384;
    const f16* wp1 = w16 + 3 * 16384;
    const f16* wl1 = w16 + 4 * 16384;
    const f16* wr1 = w16 + 5 * 16384;

    int GB = cdiv(N, 128);
    // layer 1 (gemm1 also emits x16 = f16(x))
    proj_gemm<float, true><<<GB, 256, 0, stream>>>(x, wp0, bp0, h, x16, N);
    aggregate_kernel<<<cdiv(N, 4), 256, 0, stream>>>(h, off, csr, mean, N);
    dual_gemm<f16, true><<<GB, 256, 0, stream>>>(mean, wl0, bl0, x16, wr0, y1, N);
    // layer 2
    proj_gemm<f16, false><<<GB, 256, 0, stream>>>(y1, wp1, bp1, h, nullptr, N);
    aggregate_kernel<<<cdiv(N, 4), 256, 0, stream>>>(h, off, csr, mean, N);
    dual_gemm<float, false><<<GB, 256, 0, stream>>>(mean, wl1, bl1, y1, wr1, (float*)d_out, N);
}